// Round 8
// baseline (142.654 us; speedup 1.0000x reference)
//
#include <hip/hip_runtime.h>
#include <math.h>

// Problem constants
#define BB 16384
#define TT 99
#define RR 10
#define LL 3
#define TILE 33          // 99 = 3*33
#define SROW 333         // states LDS stride (floats/row); 333%32=13, gcd(13,32)=1 -> conflict-free
#define PROW 101         // probs LDS stride (floats/row); 101%32=5 -> conflict-free
#define CROW 100         // code byte stride/row; dword stride 25, gcd(25,32)=1 -> conflict-free

// IN-LOOP register pin: asm volatile with "+v" operands, executed every
// iteration. Forces all operands live-in/live-out of EVERY step with an
// opaque redefinition: remat is illegal (def is asm), spill-around costs a
// reload+respill per iteration. This is what R7's outside-the-loop
// non-volatile KEEP failed to do (allocator spilled/remat'd; VGPR stayed 132).
#define PIN10(a0,a1,a2,a3,a4,a5,a6,a7,a8,a9)                                  \
    asm volatile("" : "+v"(a0), "+v"(a1), "+v"(a2), "+v"(a3), "+v"(a4),       \
                      "+v"(a5), "+v"(a6), "+v"(a7), "+v"(a8), "+v"(a9))

// tanh(x) = 1 - 2/(exp(2x)+1); exact limits at +-inf.
__device__ __forceinline__ float fast_tanh(float x) {
    float e = __expf(2.0f * x);
    return fmaf(-2.0f, __builtin_amdgcn_rcpf(e + 1.0f), 1.0f);
}

// One ROW PER LANE: h and ALL weights in VGPRs -> the 99-step recurrence is
// pure FMA/tanh with 10-way ILP, no memory op on the dependency chain.
// Block = 1 wave -> no barriers anywhere (per-wave DS ops are in-order).
__global__ __launch_bounds__(64, 1)
void rnn_row_kernel(const int* __restrict__ tok_ids,
                    const float* __restrict__ labels,
                    const float* __restrict__ emb,
                    const float* __restrict__ W,
                    const float* __restrict__ U,
                    const float* __restrict__ bvec,
                    const float* __restrict__ Wo,
                    const float* __restrict__ bo,
                    float* __restrict__ states_out,
                    float* __restrict__ probs_out,
                    float* __restrict__ ws)
{
    __shared__ __align__(16) float         s_st[64 * SROW];   // 85,248 B; preamble: raw labels
    __shared__ __align__(16) float         s_pr[64 * PROW];   // 25,856 B; preamble: raw tokens
    __shared__ __align__(16) unsigned char s_code[64 * CROW]; //  6,400 B  (sel<<2)|y per (row,t)
    __shared__ __align__(16) float         s_w[272];          //  1,088 B  weight staging

    const int l    = threadIdx.x;
    const int row0 = blockIdx.x * 64;

    // ---- preamble A: raw tokens -> s_pr (int4, software-pipelined groups) ----
    {
        const int4* tok4 = reinterpret_cast<const int4*>(tok_ids + (size_t)row0 * TT);
        int4* dst = reinterpret_cast<int4*>(s_pr);
        int4 buf[16];
#pragma unroll 1
        for (int g = 0; g < 2; ++g) {            // 2*16*64 = 2048 >= 1584 pieces
#pragma unroll
            for (int u = 0; u < 16; ++u) {
                const int q = l + 64 * (g * 16 + u);
                if (q < (TT * 64 / 4)) buf[u] = tok4[q];
            }
#pragma unroll
            for (int u = 0; u < 16; ++u) {
                const int q = l + 64 * (g * 16 + u);
                if (q < (TT * 64 / 4)) dst[q] = buf[u];
            }
        }
    }
    // ---- preamble B: raw labels -> s_st (float4 groups) ----
    {
        const float4* lab4 = reinterpret_cast<const float4*>(labels + (size_t)row0 * TT * LL);
        float4* dst = reinterpret_cast<float4*>(s_st);
        float4 buf[16];
#pragma unroll 1
        for (int g = 0; g < 5; ++g) {            // 5*16*64 = 5120 >= 4752 pieces
#pragma unroll
            for (int u = 0; u < 16; ++u) {
                const int q = l + 64 * (g * 16 + u);
                if (q < (TT * LL * 64 / 4)) buf[u] = lab4[q];
            }
#pragma unroll
            for (int u = 0; u < 16; ++u) {
                const int q = l + 64 * (g * 16 + u);
                if (q < (TT * LL * 64 / 4)) dst[q] = buf[u];
            }
        }
    }
    // ---- preamble C: weights -> LDS (strided so ALL 100 elems land) ----
#pragma unroll
    for (int q = 0; q < 2; ++q) {                 // covers 0..127 >= 100
        const int idx = l + 64 * q;
        if (idx < 100) { s_w[idx] = U[idx]; s_w[100 + idx] = W[idx]; }
    }
    if (l < 10)  { s_w[200 + l] = emb[10 + l];    // emb row 1
                   s_w[210 + l] = emb[20 + l];    // emb row 2
                   s_w[220 + l] = bvec[l]; }
    if (l < 30)  { s_w[230 + l] = Wo[l]; }
    if (l < 3)   { s_w[260 + l] = bo[l]; }

    // ---- preamble D: classify own row -> packed code bytes ----
    {
        const int* s_tok_i = reinterpret_cast<const int*>(s_pr);
#pragma unroll 4
        for (int t = 0; t < TT; ++t) {
            const int   tk  = s_tok_i[l * TT + t];
            const float la1 = s_st[(l * TT + t) * LL + 1];
            const float la2 = s_st[(l * TT + t) * LL + 2];
            const int   y   = (la1 > 0.5f) ? 1 : ((la2 > 0.5f) ? 2 : 0);
            s_code[l * CROW + t] = (unsigned char)((tk << 2) | y);
        }
    }

    // ---- weights: LDS -> VGPR arrays ----
    float Uv[RR][RR];
#pragma unroll
    for (int i = 0; i < RR; ++i)
#pragma unroll
        for (int j = 0; j < RR; ++j)
            Uv[i][j] = s_w[i * RR + j];

    float c1[RR], c2[RR];
#pragma unroll
    for (int j = 0; j < RR; ++j) { c1[j] = s_w[220 + j]; c2[j] = s_w[220 + j]; }
#pragma unroll
    for (int i = 0; i < RR; ++i) {
        const float e1 = s_w[200 + i];
        const float e2 = s_w[210 + i];
#pragma unroll
        for (int j = 0; j < RR; ++j) {
            const float w = s_w[100 + i * RR + j];
            c1[j] = fmaf(e1, w, c1[j]);
            c2[j] = fmaf(e2, w, c2[j]);
        }
    }
    float Woc[RR][LL];
#pragma unroll
    for (int j = 0; j < RR; ++j)
#pragma unroll
        for (int c = 0; c < LL; ++c)
            Woc[j][c] = s_w[230 + j * LL + c];
    float bo0 = s_w[260], bo1 = s_w[261], bo2 = s_w[262];

    // ---- main sequential loop: register-only recurrence ----
    float h[RR];
#pragma unroll
    for (int j = 0; j < RR; ++j) h[j] = 0.0f;
    float loss_acc = 0.0f;
    int   corr = 0;

    int code = (int)s_code[l * CROW];            // prefetch t=0

#pragma unroll 1
    for (int k = 0; k < 3; ++k) {
#pragma unroll 1
        for (int tt = 0; tt < TILE; ++tt) {
            // ---- IN-LOOP PINS: all 153 weight floats live through every
            // iteration; emits zero instructions. ----
            PIN10(Uv[0][0],Uv[0][1],Uv[0][2],Uv[0][3],Uv[0][4],Uv[0][5],Uv[0][6],Uv[0][7],Uv[0][8],Uv[0][9]);
            PIN10(Uv[1][0],Uv[1][1],Uv[1][2],Uv[1][3],Uv[1][4],Uv[1][5],Uv[1][6],Uv[1][7],Uv[1][8],Uv[1][9]);
            PIN10(Uv[2][0],Uv[2][1],Uv[2][2],Uv[2][3],Uv[2][4],Uv[2][5],Uv[2][6],Uv[2][7],Uv[2][8],Uv[2][9]);
            PIN10(Uv[3][0],Uv[3][1],Uv[3][2],Uv[3][3],Uv[3][4],Uv[3][5],Uv[3][6],Uv[3][7],Uv[3][8],Uv[3][9]);
            PIN10(Uv[4][0],Uv[4][1],Uv[4][2],Uv[4][3],Uv[4][4],Uv[4][5],Uv[4][6],Uv[4][7],Uv[4][8],Uv[4][9]);
            PIN10(Uv[5][0],Uv[5][1],Uv[5][2],Uv[5][3],Uv[5][4],Uv[5][5],Uv[5][6],Uv[5][7],Uv[5][8],Uv[5][9]);
            PIN10(Uv[6][0],Uv[6][1],Uv[6][2],Uv[6][3],Uv[6][4],Uv[6][5],Uv[6][6],Uv[6][7],Uv[6][8],Uv[6][9]);
            PIN10(Uv[7][0],Uv[7][1],Uv[7][2],Uv[7][3],Uv[7][4],Uv[7][5],Uv[7][6],Uv[7][7],Uv[7][8],Uv[7][9]);
            PIN10(Uv[8][0],Uv[8][1],Uv[8][2],Uv[8][3],Uv[8][4],Uv[8][5],Uv[8][6],Uv[8][7],Uv[8][8],Uv[8][9]);
            PIN10(Uv[9][0],Uv[9][1],Uv[9][2],Uv[9][3],Uv[9][4],Uv[9][5],Uv[9][6],Uv[9][7],Uv[9][8],Uv[9][9]);
            PIN10(c1[0],c1[1],c1[2],c1[3],c1[4],c1[5],c1[6],c1[7],c1[8],c1[9]);
            PIN10(c2[0],c2[1],c2[2],c2[3],c2[4],c2[5],c2[6],c2[7],c2[8],c2[9]);
            PIN10(Woc[0][0],Woc[0][1],Woc[0][2],Woc[1][0],Woc[1][1],Woc[1][2],Woc[2][0],Woc[2][1],Woc[2][2],Woc[3][0]);
            PIN10(Woc[3][1],Woc[3][2],Woc[4][0],Woc[4][1],Woc[4][2],Woc[5][0],Woc[5][1],Woc[5][2],Woc[6][0],Woc[6][1]);
            PIN10(Woc[6][2],Woc[7][0],Woc[7][1],Woc[7][2],Woc[8][0],Woc[8][1],Woc[8][2],Woc[9][0],Woc[9][1],Woc[9][2]);
            asm volatile("" : "+v"(bo0), "+v"(bo1), "+v"(bo2));

            const int t   = k * TILE + tt;
            const int cur = code;
            const int tn  = (t + 1 < TT) ? t + 1 : t;
            code = (int)s_code[l * CROW + tn];   // prefetch next step

            const int  sel  = cur >> 2;
            const int  y    = cur & 3;
            const bool is1  = (sel == 1);
            const bool live = (sel != 0);

            float a[RR];
#pragma unroll
            for (int j = 0; j < RR; ++j) a[j] = is1 ? c1[j] : c2[j];
#pragma unroll
            for (int i = 0; i < RR; ++i) {
                const float hi = h[i];
#pragma unroll
                for (int j = 0; j < RR; ++j)
                    a[j] = fmaf(hi, Uv[i][j], a[j]);
            }
#pragma unroll
            for (int j = 0; j < RR; ++j) {
                const float hn = fast_tanh(a[j]);
                h[j] = live ? hn : h[j];          // Keras masking: carry h
            }

            // stage states (fire-and-forget, conflict-free stride)
            float* sp = &s_st[l * SROW + tt * RR];
#pragma unroll
            for (int j = 0; j < RR; ++j) sp[j] = h[j];

            // logits (10x3); softmax WITHOUT max-subtract (|logit| <~ 3)
            float l0 = bo0, l1 = bo1, l2 = bo2;
#pragma unroll
            for (int j = 0; j < RR; ++j) {
                l0 = fmaf(h[j], Woc[j][0], l0);
                l1 = fmaf(h[j], Woc[j][1], l1);
                l2 = fmaf(h[j], Woc[j][2], l2);
            }
            const float e0 = __expf(l0), e1 = __expf(l1), e2 = __expf(l2);
            const float S  = e0 + e1 + e2;
            const float rs = __builtin_amdgcn_rcpf(S);
            float* pp = &s_pr[l * PROW + tt * LL];
            pp[0] = e0 * rs; pp[1] = e1 * rs; pp[2] = e2 * rs;

            // loss: -log(clip(p_y)) == min(logS - l_y, -log(1e-7))
            const float ly   = (y == 0) ? l0 : ((y == 1) ? l1 : l2);
            const float term = fminf(__logf(S) - ly, 16.11809565f);
            loss_acc += term;

            // accuracy: argmax(probs) == argmax(logits) (monotonic, same ties)
            int ap = 0; float pm = l0;
            if (l1 > pm) { ap = 1; pm = l1; }
            if (l2 > pm) { ap = 2; }
            corr += (ap == y) ? 1 : 0;
        }

        // ---- flush states tile: LDS -> global, coalesced float2 ----
        {
            const size_t sb = (size_t)row0 * (TT * RR) + (size_t)k * TILE * RR;
#pragma unroll 4
            for (int i = 0; i < 165; ++i) {
                const int q  = l + 64 * i;
                const int r  = q / 165;
                const int m2 = q - r * 165;
                const float v0 = s_st[r * SROW + 2 * m2];
                const float v1 = s_st[r * SROW + 2 * m2 + 1];
                *reinterpret_cast<float2*>(
                    &states_out[sb + (size_t)r * (TT * RR) + 2 * m2]) = make_float2(v0, v1);
            }
        }
        // ---- flush probs tile: coalesced dwords ----
        {
            const size_t pb = (size_t)row0 * (TT * LL) + (size_t)k * TILE * LL;
#pragma unroll 4
            for (int i = 0; i < 99; ++i) {
                const int q  = l + 64 * i;
                const int r  = q / 99;
                const int m1 = q - r * 99;
                probs_out[pb + (size_t)r * (TT * LL) + m1] = s_pr[r * PROW + m1];
            }
        }
        // next tile reuses s_st/s_pr: same-wave DS ordering guarantees safety
    }

    // ---- wave reduction -> one partial per block (deterministic) ----
    float ls = loss_acc;
    float cs = (float)corr;
#pragma unroll
    for (int off = 32; off > 0; off >>= 1) {
        ls += __shfl_down(ls, off, 64);
        cs += __shfl_down(cs, off, 64);
    }
    if (l == 0) {
        ws[blockIdx.x]       = ls;
        ws[256 + blockIdx.x] = cs;
    }
}

__global__ __launch_bounds__(256)
void finalize_kernel(const float* __restrict__ ws, float* __restrict__ out_tail)
{
    __shared__ float sl[4], sc[4];
    const int t = threadIdx.x;
    float ls = ws[t];
    float cs = ws[256 + t];
#pragma unroll
    for (int off = 32; off > 0; off >>= 1) {
        ls += __shfl_down(ls, off, 64);
        cs += __shfl_down(cs, off, 64);
    }
    if ((t & 63) == 0) { sl[t >> 6] = ls; sc[t >> 6] = cs; }
    __syncthreads();
    if (t == 0) {
        const float L = sl[0] + sl[1] + sl[2] + sl[3];
        const float C = sc[0] + sc[1] + sc[2] + sc[3];
        const float inv = 1.0f / (float)((size_t)BB * TT);
        out_tail[0] = C * inv;   // accuracy
        out_tail[1] = L * inv;   // loss
    }
}

extern "C" void kernel_launch(void* const* d_in, const int* in_sizes, int n_in,
                              void* d_out, int out_size, void* d_ws, size_t ws_size,
                              hipStream_t stream)
{
    const int*   tok    = (const int*)  d_in[0];
    const float* labels = (const float*)d_in[1];
    // d_in[2] = mask (unused by reference math)
    const float* emb = (const float*)d_in[3];
    const float* W   = (const float*)d_in[4];
    const float* U   = (const float*)d_in[5];
    const float* bv  = (const float*)d_in[6];
    const float* Wo  = (const float*)d_in[7];
    const float* bo  = (const float*)d_in[8];

    float* out    = (float*)d_out;
    float* states = out;                                  // [B,T,10]
    float* probs  = out + (size_t)BB * TT * RR;           // [B,T,3]
    float* tail   = out + (size_t)BB * TT * (RR + LL);    // accuracy, loss
    float* ws     = (float*)d_ws;                         // 512 floats used

    rnn_row_kernel<<<BB / 64, 64, 0, stream>>>(tok, labels, emb, W, U, bv, Wo, bo,
                                               states, probs, ws);
    finalize_kernel<<<1, 256, 0, stream>>>(ws, tail);
}

// Round 9
// 138.016 us; speedup vs baseline: 1.0336x; 1.0336x over previous
//
#include <hip/hip_runtime.h>
#include <math.h>

// Problem constants
#define BB 16384
#define TT 99
#define RR 10
#define LL 3
#define TILE 33          // 99 = 3*33, processed as 3 chunks of 11 unrolled steps
#define SROW 334         // states LDS stride (floats/row); EVEN -> float2-aligned b64 writes;
                         // 14l mod 32 = 16 bank-pairs x 4 lanes = 4-phase minimum -> conflict-free
#define PROW 101         // probs LDS stride (floats/row); 101%32=5 -> conflict-free
#define CROW 100         // code byte stride/row; dword stride 25, gcd(25,32)=1 -> conflict-free

// tanh(x) = 1 - 2/(exp(2x)+1); exact limits at +-inf.
__device__ __forceinline__ float fast_tanh(float x) {
    float e = __expf(2.0f * x);
    return fmaf(-2.0f, __builtin_amdgcn_rcpf(e + 1.0f), 1.0f);
}

// One ROW PER LANE. R9 strategy: the compiler refuses to keep ~150
// wave-uniform weight floats live across a rolled loop (caps at ~132 VGPR,
// refetches per iteration -> R4/R6/R7/R8 all ~3400 cy/step). Instead of
// fighting the allocator, UNROLL 11 steps per chunk: within straight-line
// code the ~150 ds_reads are CSE'd once per chunk, amortizing the refetch
// 11x while peak pressure stays at the allocator's preferred level.
__global__ __launch_bounds__(64, 1)
void rnn_row_kernel(const int* __restrict__ tok_ids,
                    const float* __restrict__ labels,
                    const float* __restrict__ emb,
                    const float* __restrict__ W,
                    const float* __restrict__ U,
                    const float* __restrict__ bvec,
                    const float* __restrict__ Wo,
                    const float* __restrict__ bo,
                    float* __restrict__ states_out,
                    float* __restrict__ probs_out,
                    float* __restrict__ ws)
{
    __shared__ __align__(16) float         s_st[64 * SROW];   // 85,504 B; preamble: raw labels
    __shared__ __align__(16) float         s_pr[64 * PROW];   // 25,856 B; preamble: raw tokens
    __shared__ __align__(16) unsigned char s_code[64 * CROW]; //  6,400 B  (sel<<2)|y per (row,t)
    __shared__ __align__(16) float         s_w[272];          //  1,088 B  weight staging

    const int l    = threadIdx.x;
    const int row0 = blockIdx.x * 64;

    // ---- preamble A: raw tokens -> s_pr (int4, software-pipelined groups) ----
    {
        const int4* tok4 = reinterpret_cast<const int4*>(tok_ids + (size_t)row0 * TT);
        int4* dst = reinterpret_cast<int4*>(s_pr);
        int4 buf[16];
#pragma unroll 1
        for (int g = 0; g < 2; ++g) {            // 2*16*64 = 2048 >= 1584 pieces
#pragma unroll
            for (int u = 0; u < 16; ++u) {
                const int q = l + 64 * (g * 16 + u);
                if (q < (TT * 64 / 4)) buf[u] = tok4[q];
            }
#pragma unroll
            for (int u = 0; u < 16; ++u) {
                const int q = l + 64 * (g * 16 + u);
                if (q < (TT * 64 / 4)) dst[q] = buf[u];
            }
        }
    }
    // ---- preamble B: raw labels -> s_st (float4 groups) ----
    {
        const float4* lab4 = reinterpret_cast<const float4*>(labels + (size_t)row0 * TT * LL);
        float4* dst = reinterpret_cast<float4*>(s_st);
        float4 buf[16];
#pragma unroll 1
        for (int g = 0; g < 5; ++g) {            // 5*16*64 = 5120 >= 4752 pieces
#pragma unroll
            for (int u = 0; u < 16; ++u) {
                const int q = l + 64 * (g * 16 + u);
                if (q < (TT * LL * 64 / 4)) buf[u] = lab4[q];
            }
#pragma unroll
            for (int u = 0; u < 16; ++u) {
                const int q = l + 64 * (g * 16 + u);
                if (q < (TT * LL * 64 / 4)) dst[q] = buf[u];
            }
        }
    }
    // ---- preamble C: weights -> LDS (strided so ALL 100 elems land) ----
#pragma unroll
    for (int q = 0; q < 2; ++q) {                 // covers 0..127 >= 100
        const int idx = l + 64 * q;
        if (idx < 100) { s_w[idx] = U[idx]; s_w[100 + idx] = W[idx]; }
    }
    if (l < 10)  { s_w[200 + l] = emb[10 + l];    // emb row 1
                   s_w[210 + l] = emb[20 + l];    // emb row 2
                   s_w[220 + l] = bvec[l]; }
    if (l < 30)  { s_w[230 + l] = Wo[l]; }
    if (l < 3)   { s_w[260 + l] = bo[l]; }

    // ---- preamble D: classify own row -> packed code bytes ----
    {
        const int* s_tok_i = reinterpret_cast<const int*>(s_pr);
#pragma unroll 4
        for (int t = 0; t < TT; ++t) {
            const int   tk  = s_tok_i[l * TT + t];
            const float la1 = s_st[(l * TT + t) * LL + 1];
            const float la2 = s_st[(l * TT + t) * LL + 2];
            const int   y   = (la1 > 0.5f) ? 1 : ((la2 > 0.5f) ? 2 : 0);
            s_code[l * CROW + t] = (unsigned char)((tk << 2) | y);
        }
    }

    // ---- weights: LDS -> VGPR arrays (CSE'd once per unrolled chunk) ----
    float Uv[RR][RR];
#pragma unroll
    for (int i = 0; i < RR; ++i)
#pragma unroll
        for (int j = 0; j < RR; ++j)
            Uv[i][j] = s_w[i * RR + j];

    float c1[RR], c2[RR];
#pragma unroll
    for (int j = 0; j < RR; ++j) { c1[j] = s_w[220 + j]; c2[j] = s_w[220 + j]; }
#pragma unroll
    for (int i = 0; i < RR; ++i) {
        const float e1 = s_w[200 + i];
        const float e2 = s_w[210 + i];
#pragma unroll
        for (int j = 0; j < RR; ++j) {
            const float w = s_w[100 + i * RR + j];
            c1[j] = fmaf(e1, w, c1[j]);
            c2[j] = fmaf(e2, w, c2[j]);
        }
    }
    float Woc[RR][LL];
#pragma unroll
    for (int j = 0; j < RR; ++j)
#pragma unroll
        for (int c = 0; c < LL; ++c)
            Woc[j][c] = s_w[230 + j * LL + c];
    const float bo0 = s_w[260], bo1 = s_w[261], bo2 = s_w[262];

    // ---- main sequential loop: 3 tiles x (3 chunks x 11 unrolled steps) ----
    float h[RR];
#pragma unroll
    for (int j = 0; j < RR; ++j) h[j] = 0.0f;
    float loss_acc = 0.0f;
    int   corr = 0;

    int code = (int)s_code[l * CROW];            // prefetch t=0

#pragma unroll 1
    for (int k = 0; k < 3; ++k) {
#pragma unroll 1
        for (int tb = 0; tb < 3; ++tb) {
#pragma unroll
            for (int u = 0; u < 11; ++u) {       // UNROLLED: weights fetched once/chunk
                const int tt  = tb * 11 + u;
                const int t   = k * TILE + tt;
                const int cur = code;
                const int tn  = (t + 1 < TT) ? t + 1 : t;
                code = (int)s_code[l * CROW + tn];   // prefetch next step

                const int  sel  = cur >> 2;
                const int  y    = cur & 3;
                const bool is1  = (sel == 1);
                const bool live = (sel != 0);

                float a[RR];
#pragma unroll
                for (int j = 0; j < RR; ++j) a[j] = is1 ? c1[j] : c2[j];
#pragma unroll
                for (int i = 0; i < RR; ++i) {
                    const float hi = h[i];
#pragma unroll
                    for (int j = 0; j < RR; ++j)
                        a[j] = fmaf(hi, Uv[i][j], a[j]);
                }
#pragma unroll
                for (int j = 0; j < RR; ++j) {
                    const float hn = fast_tanh(a[j]);
                    h[j] = live ? hn : h[j];          // Keras masking: carry h
                }

                // stage states: 5x ds_write_b64 (SROW even -> 8B aligned)
                float* sp = &s_st[l * SROW + tt * RR];
#pragma unroll
                for (int j = 0; j < RR; j += 2)
                    *reinterpret_cast<float2*>(sp + j) = make_float2(h[j], h[j + 1]);

                // logits (10x3); softmax WITHOUT max-subtract (|logit| <~ 3)
                float l0 = bo0, l1 = bo1, l2 = bo2;
#pragma unroll
                for (int j = 0; j < RR; ++j) {
                    l0 = fmaf(h[j], Woc[j][0], l0);
                    l1 = fmaf(h[j], Woc[j][1], l1);
                    l2 = fmaf(h[j], Woc[j][2], l2);
                }
                const float e0 = __expf(l0), e1 = __expf(l1), e2 = __expf(l2);
                const float S  = e0 + e1 + e2;
                const float rs = __builtin_amdgcn_rcpf(S);
                float* pp = &s_pr[l * PROW + tt * LL];
                pp[0] = e0 * rs; pp[1] = e1 * rs; pp[2] = e2 * rs;

                // loss: -log(clip(p_y)) == min(logS - l_y, -log(1e-7))
                const float ly   = (y == 0) ? l0 : ((y == 1) ? l1 : l2);
                loss_acc += fminf(__logf(S) - ly, 16.11809565f);

                // accuracy: argmax(probs) == argmax(logits)
                int ap = 0; float pm = l0;
                if (l1 > pm) { ap = 1; pm = l1; }
                if (l2 > pm) { ap = 2; }
                corr += (ap == y) ? 1 : 0;
            }
        }

        // ---- flush states tile: LDS -> global, coalesced float2 ----
        {
            const size_t sb = (size_t)row0 * (TT * RR) + (size_t)k * TILE * RR;
#pragma unroll 4
            for (int i = 0; i < 165; ++i) {
                const int q  = l + 64 * i;
                const int r  = q / 165;
                const int m2 = q - r * 165;
                const float v0 = s_st[r * SROW + 2 * m2];
                const float v1 = s_st[r * SROW + 2 * m2 + 1];
                *reinterpret_cast<float2*>(
                    &states_out[sb + (size_t)r * (TT * RR) + 2 * m2]) = make_float2(v0, v1);
            }
        }
        // ---- flush probs tile: coalesced dwords ----
        {
            const size_t pb = (size_t)row0 * (TT * LL) + (size_t)k * TILE * LL;
#pragma unroll 4
            for (int i = 0; i < 99; ++i) {
                const int q  = l + 64 * i;
                const int r  = q / 99;
                const int m1 = q - r * 99;
                probs_out[pb + (size_t)r * (TT * LL) + m1] = s_pr[r * PROW + m1];
            }
        }
        // next tile reuses s_st/s_pr: same-wave DS ordering guarantees safety
    }

    // ---- wave reduction -> one partial per block (deterministic) ----
    float ls = loss_acc;
    float cs = (float)corr;
#pragma unroll
    for (int off = 32; off > 0; off >>= 1) {
        ls += __shfl_down(ls, off, 64);
        cs += __shfl_down(cs, off, 64);
    }
    if (l == 0) {
        ws[blockIdx.x]       = ls;
        ws[256 + blockIdx.x] = cs;
    }
}

__global__ __launch_bounds__(256)
void finalize_kernel(const float* __restrict__ ws, float* __restrict__ out_tail)
{
    __shared__ float sl[4], sc[4];
    const int t = threadIdx.x;
    float ls = ws[t];
    float cs = ws[256 + t];
#pragma unroll
    for (int off = 32; off > 0; off >>= 1) {
        ls += __shfl_down(ls, off, 64);
        cs += __shfl_down(cs, off, 64);
    }
    if ((t & 63) == 0) { sl[t >> 6] = ls; sc[t >> 6] = cs; }
    __syncthreads();
    if (t == 0) {
        const float L = sl[0] + sl[1] + sl[2] + sl[3];
        const float C = sc[0] + sc[1] + sc[2] + sc[3];
        const float inv = 1.0f / (float)((size_t)BB * TT);
        out_tail[0] = C * inv;   // accuracy
        out_tail[1] = L * inv;   // loss
    }
}

extern "C" void kernel_launch(void* const* d_in, const int* in_sizes, int n_in,
                              void* d_out, int out_size, void* d_ws, size_t ws_size,
                              hipStream_t stream)
{
    const int*   tok    = (const int*)  d_in[0];
    const float* labels = (const float*)d_in[1];
    // d_in[2] = mask (unused by reference math)
    const float* emb = (const float*)d_in[3];
    const float* W   = (const float*)d_in[4];
    const float* U   = (const float*)d_in[5];
    const float* bv  = (const float*)d_in[6];
    const float* Wo  = (const float*)d_in[7];
    const float* bo  = (const float*)d_in[8];

    float* out    = (float*)d_out;
    float* states = out;                                  // [B,T,10]
    float* probs  = out + (size_t)BB * TT * RR;           // [B,T,3]
    float* tail   = out + (size_t)BB * TT * (RR + LL);    // accuracy, loss
    float* ws     = (float*)d_ws;                         // 512 floats used

    rnn_row_kernel<<<BB / 64, 64, 0, stream>>>(tok, labels, emb, W, U, bv, Wo, bo,
                                               states, probs, ws);
    finalize_kernel<<<1, 256, 0, stream>>>(ws, tail);
}